// Round 5
// baseline (763.597 us; speedup 1.0000x reference)
//
#include <hip/hip_runtime.h>

#define N_NODES 100000
#define N_EDGES 1600000
#define IN_F 128
#define H_F 64
#define NSLICE 8
#define SLICE_N (N_NODES / NSLICE)      // 12500
#define NCHUNK 16
#define CHUNK_E (N_EDGES / NCHUNK)      // 100000

// ---------------- LDS histogram over one (slice, chunk) pair ----------------
// bid&7 = slice (maps to one XCD under round-robin), bid>>3 = edge chunk.
// Adjacent bids read the same chunk nearly simultaneously -> L2/L3-served.
// All histogram atomics are LDS atomics; flush is plain coalesced stores to
// partial[chunk][node]. Zero global atomics.
__global__ __launch_bounds__(256) void hist_kernel(
        const int* __restrict__ idx, int* __restrict__ partial) {
    __shared__ int hist[SLICE_N];
    int slice = blockIdx.x & (NSLICE - 1);
    int chunk = blockIdx.x >> 3;
    int lo = slice * SLICE_N;
    for (int t = threadIdx.x; t < SLICE_N; t += 256) hist[t] = 0;
    __syncthreads();
    int e0 = chunk * CHUNK_E;
    for (int e = e0 + threadIdx.x; e < e0 + CHUNK_E; e += 256) {
        int d = idx[e] - lo;
        if ((unsigned)d < (unsigned)SLICE_N) atomicAdd(&hist[d], 1);
    }
    __syncthreads();
    int* dstp = partial + (size_t)chunk * N_NODES + lo;
    for (int t = threadIdx.x; t < SLICE_N; t += 256) dstp[t] = hist[t];
}

// ---------------- reduce partials -> degrees + norms ----------------
__global__ void reduce_norm_kernel(const int* __restrict__ psrc, const int* __restrict__ pdst,
                                   float* __restrict__ out_norm, float* __restrict__ in_norm,
                                   int* __restrict__ deg_dst, int N) {
    int i = blockIdx.x * blockDim.x + threadIdx.x;
    if (i >= N) return;
    int ds = 0, dd = 0;
#pragma unroll
    for (int c = 0; c < NCHUNK; c++) {
        ds += psrc[(size_t)c * N_NODES + i];
        dd += pdst[(size_t)c * N_NODES + i];
    }
    deg_dst[i] = dd;
    out_norm[i] = rsqrtf((float)max(ds, 1));
    in_norm[i]  = rsqrtf((float)max(dd, 1));
}

// ---------------- exclusive scan (3-phase) ----------------
__global__ void scan_block_kernel(const int* __restrict__ deg, int* __restrict__ out,
                                  int* __restrict__ bsums, int N) {
    __shared__ int temp[256];
    int tid = threadIdx.x;
    int i = blockIdx.x * 256 + tid;
    int v = (i < N) ? deg[i] : 0;
    temp[tid] = v;
    __syncthreads();
    for (int off = 1; off < 256; off <<= 1) {
        int t = (tid >= off) ? temp[tid - off] : 0;
        __syncthreads();
        temp[tid] += t;
        __syncthreads();
    }
    int excl = (tid > 0) ? temp[tid - 1] : 0;
    if (i < N) out[i] = excl;
    if (tid == 255) bsums[blockIdx.x] = temp[255];
}

__global__ void scan_sums_kernel(int* __restrict__ bsums, int B) {
    __shared__ int temp[512];
    int tid = threadIdx.x;
    int v = (tid < B) ? bsums[tid] : 0;
    temp[tid] = v;
    __syncthreads();
    for (int off = 1; off < 512; off <<= 1) {
        int t = (tid >= off) ? temp[tid - off] : 0;
        __syncthreads();
        temp[tid] += t;
        __syncthreads();
    }
    int excl = (tid > 0) ? temp[tid - 1] : 0;
    if (tid < B) bsums[tid] = excl;
}

__global__ void scan_add_kernel(int* __restrict__ row_off, const int* __restrict__ bsums,
                                int N, int E) {
    int i = blockIdx.x * 256 + threadIdx.x;
    if (i < N) row_off[i] += bsums[i >> 8];
    if (i == 0) row_off[N] = E;
}

// ---------------- per-chunk base offsets: pdst[c][i] <- row_off[i] + sum_{c'<c} pdst[c'][i] ----------------
__global__ void chunk_base_kernel(int* __restrict__ pdst, const int* __restrict__ row_off, int N) {
    int i = blockIdx.x * blockDim.x + threadIdx.x;
    if (i >= N) return;
    int b = row_off[i];
#pragma unroll
    for (int c = 0; c < NCHUNK; c++) {
        int t = pdst[(size_t)c * N_NODES + i];
        pdst[(size_t)c * N_NODES + i] = b;
        b += t;
    }
}

// ---------------- counting-sort scatter: LDS cursor, plain global stores ----------------
// Slice s blocks all have bid&7==s -> same XCD -> that slice's csr region
// [row_off[lo], row_off[hi]) is written from one XCD only: single writeback.
__global__ __launch_bounds__(256) void scatter_sort_kernel(
        const int* __restrict__ src, const int* __restrict__ dst,
        const int* __restrict__ base, int* __restrict__ csr_src) {
    __shared__ int cur[SLICE_N];
    int slice = blockIdx.x & (NSLICE - 1);
    int chunk = blockIdx.x >> 3;
    int lo = slice * SLICE_N;
    const int* bp = base + (size_t)chunk * N_NODES + lo;
    for (int t = threadIdx.x; t < SLICE_N; t += 256) cur[t] = bp[t];
    __syncthreads();
    int e0 = chunk * CHUNK_E;
    for (int e = e0 + threadIdx.x; e < e0 + CHUNK_E; e += 256) {
        int d = dst[e] - lo;
        if ((unsigned)d < (unsigned)SLICE_N) {
            int p = atomicAdd(&cur[d], 1);   // LDS atomic
            csr_src[p] = src[e];
        }
    }
}

// ---------------- thread-per-row GEMM, 32-col half per blockIdx.y ----------------
template <int K>
__global__ __launch_bounds__(256, 4) void gemm_tpr_kernel(
        const float* __restrict__ in, const float* __restrict__ W,
        const float* __restrict__ scale, float* __restrict__ out, int N) {
    int r = blockIdx.x * blockDim.x + threadIdx.x;
    if (r >= N) return;
    const int h = blockIdx.y * 32;

    float acc[32];
#pragma unroll
    for (int j = 0; j < 32; j++) acc[j] = 0.f;

    const float* row = in + (size_t)r * K;
#pragma unroll 4
    for (int k = 0; k < K; k += 4) {
        float4 a = *reinterpret_cast<const float4*>(row + k);
        const float* w0 = W + (size_t)k * 64 + h;
#pragma unroll
        for (int j = 0; j < 32; j++) acc[j] = fmaf(a.x, w0[j], acc[j]);
#pragma unroll
        for (int j = 0; j < 32; j++) acc[j] = fmaf(a.y, w0[64 + j], acc[j]);
#pragma unroll
        for (int j = 0; j < 32; j++) acc[j] = fmaf(a.z, w0[128 + j], acc[j]);
#pragma unroll
        for (int j = 0; j < 32; j++) acc[j] = fmaf(a.w, w0[192 + j], acc[j]);
    }

    float s = scale[r];
    float4* o = reinterpret_cast<float4*>(out + (size_t)r * 64 + h);
#pragma unroll
    for (int j = 0; j < 32; j += 4) {
        float4 v;
        v.x = acc[j + 0] * s;
        v.y = acc[j + 1] * s;
        v.z = acc[j + 2] * s;
        v.w = acc[j + 3] * s;
        o[j >> 2] = v;
    }
}

// ---------------- CSR aggregation (one wave per node), optional fused 64->2 head ----------------
template <bool FUSE_HEAD>
__global__ __launch_bounds__(256) void agg_kernel(
        const float* __restrict__ X, const int* __restrict__ row_off,
        const int* __restrict__ csr_src, const float* __restrict__ in_norm,
        const float* __restrict__ bias, const float* __restrict__ Wm,
        const float* __restrict__ bm, float* __restrict__ out, int N) {
    int lane = threadIdx.x & 63;
    int wave = threadIdx.x >> 6;
    int v = blockIdx.x * (blockDim.x >> 6) + wave;
    if (v >= N) return;

    int start = row_off[v];
    int end = row_off[v + 1];
    float acc = 0.f;
    for (int base = start; base < end; base += 64) {
        int idx = base + lane;
        int s_e = (idx < end) ? csr_src[idx] : 0;
        int cnt = min(64, end - base);
        for (int t = 0; t < cnt; t++) {
            int s = __shfl(s_e, t);
            acc += X[(size_t)s * 64 + lane];
        }
    }
    float h = fmaf(acc, in_norm[v], bias[lane]);
    h = fmaxf(h, 0.f);

    if (!FUSE_HEAD) {
        out[(size_t)v * 64 + lane] = h;
    } else {
        float p0 = h * Wm[lane * 2 + 0];
        float p1 = h * Wm[lane * 2 + 1];
#pragma unroll
        for (int off = 32; off > 0; off >>= 1) {
            p0 += __shfl_xor(p0, off);
            p1 += __shfl_xor(p1, off);
        }
        if (lane == 0) {
            out[(size_t)v * 2 + 0] = p0 + bm[0];
            out[(size_t)v * 2 + 1] = p1 + bm[1];
        }
    }
}

extern "C" void kernel_launch(void* const* d_in, const int* in_sizes, int n_in,
                              void* d_out, int out_size, void* d_ws, size_t ws_size,
                              hipStream_t stream) {
    const float* feature = (const float*)d_in[0];
    const float* W1 = (const float*)d_in[1];
    const float* b1 = (const float*)d_in[2];
    const float* W2 = (const float*)d_in[3];
    const float* b2 = (const float*)d_in[4];
    const float* Wm = (const float*)d_in[5];
    const float* bm = (const float*)d_in[6];
    const int* src = (const int*)d_in[7];
    const int* dst = (const int*)d_in[8];
    float* out = (float*)d_out;

    const int N = N_NODES, E = N_EDGES;

    char* p = (char*)d_ws;
    int* deg_dst = (int*)p;      p += (size_t)N * 4;
    float* out_norm = (float*)p; p += (size_t)N * 4;
    float* in_norm = (float*)p;  p += (size_t)N * 4;
    int* row_off = (int*)p;      p += (size_t)(N + 1) * 4;
    int* bsums = (int*)p;        p += 512 * 4;
    int* csr_src = (int*)p;      p += (size_t)E * 4;
    float* X = (float*)p;        p += (size_t)N * 64 * 4;
    float* H = (float*)p;        p += (size_t)N * 64 * 4;
    // partial tables alias X (X is first written by gemm1, after scatter)
    int* pdst = (int*)X;                               // [NCHUNK][N]
    int* psrc = (int*)X + (size_t)NCHUNK * N_NODES;    // [NCHUNK][N]

    hist_kernel<<<NSLICE * NCHUNK, 256, 0, stream>>>(dst, pdst);
    hist_kernel<<<NSLICE * NCHUNK, 256, 0, stream>>>(src, psrc);
    reduce_norm_kernel<<<(N + 255) / 256, 256, 0, stream>>>(psrc, pdst, out_norm, in_norm,
                                                            deg_dst, N);

    int nScanBlocks = (N + 255) / 256;  // 391
    scan_block_kernel<<<nScanBlocks, 256, 0, stream>>>(deg_dst, row_off, bsums, N);
    scan_sums_kernel<<<1, 512, 0, stream>>>(bsums, nScanBlocks);
    scan_add_kernel<<<nScanBlocks, 256, 0, stream>>>(row_off, bsums, N, E);

    chunk_base_kernel<<<(N + 255) / 256, 256, 0, stream>>>(pdst, row_off, N);
    scatter_sort_kernel<<<NSLICE * NCHUNK, 256, 0, stream>>>(src, dst, pdst, csr_src);

    dim3 ggrid((N + 255) / 256, 2);
    // layer 1
    gemm_tpr_kernel<128><<<ggrid, 256, 0, stream>>>(feature, W1, out_norm, X, N);
    agg_kernel<false><<<(N + 3) / 4, 256, 0, stream>>>(X, row_off, csr_src, in_norm, b1,
                                                       nullptr, nullptr, H, N);
    // layer 2
    gemm_tpr_kernel<64><<<ggrid, 256, 0, stream>>>(H, W2, out_norm, X, N);
    // fused head
    agg_kernel<true><<<(N + 3) / 4, 256, 0, stream>>>(X, row_off, csr_src, in_norm, b2,
                                                      Wm, bm, out, N);
}

// Round 6
// 470.400 us; speedup vs baseline: 1.6233x; 1.6233x over previous
//
#include <hip/hip_runtime.h>

#define N_NODES 100000
#define N_EDGES 1600000
#define IN_F 128
#define H_F 64

#define NCHUNK 64
#define CHUNK_E (N_EDGES / NCHUNK)      // 25000

// histogram slicing: 2x u16 packed per u32 -> 25000 nodes in 50KB LDS
#define NSLICE_H 4
#define SLICE_H (N_NODES / NSLICE_H)    // 25000
// scatter slicing: u32 cursors -> 12500 nodes in 50KB LDS
#define NSLICE_S 8
#define SLICE_S (N_NODES / NSLICE_S)    // 12500

// ---------------- LDS histogram, packed u16 pairs ----------------
// bid&3 = node slice, bid>>2 = edge chunk. Per-chunk per-node count <= 25000
// so u16 halves never overflow. Zero global atomics.
__global__ __launch_bounds__(256) void hist_kernel(
        const int* __restrict__ idx, unsigned* __restrict__ partial) {
    __shared__ unsigned hist[SLICE_H / 2];
    int slice = blockIdx.x & (NSLICE_H - 1);
    int chunk = blockIdx.x >> 2;
    int lo = slice * SLICE_H;
    for (int t = threadIdx.x; t < SLICE_H / 2; t += 256) hist[t] = 0;
    __syncthreads();
    int e0 = chunk * CHUNK_E;
    for (int e = e0 + threadIdx.x; e < e0 + CHUNK_E; e += 256) {
        int d = idx[e] - lo;
        if ((unsigned)d < (unsigned)SLICE_H)
            atomicAdd(&hist[d >> 1], 1u << ((d & 1) << 4));
    }
    __syncthreads();
    unsigned* dstp = partial + (size_t)chunk * (N_NODES / 2) + (lo >> 1);
    for (int t = threadIdx.x; t < SLICE_H / 2; t += 256) dstp[t] = hist[t];
}

// ---------------- reduce packed partials -> degrees + norms ----------------
__global__ void reduce_norm_kernel(const unsigned* __restrict__ psrc,
                                   const unsigned* __restrict__ pdst,
                                   float* __restrict__ out_norm, float* __restrict__ in_norm,
                                   int* __restrict__ deg_dst, int N) {
    int i = blockIdx.x * blockDim.x + threadIdx.x;
    if (i >= N) return;
    int half = i >> 1, sh = (i & 1) << 4;
    int ds = 0, dd = 0;
#pragma unroll
    for (int c = 0; c < NCHUNK; c++) {
        ds += (psrc[(size_t)c * (N_NODES / 2) + half] >> sh) & 0xFFFF;
        dd += (pdst[(size_t)c * (N_NODES / 2) + half] >> sh) & 0xFFFF;
    }
    deg_dst[i] = dd;
    out_norm[i] = rsqrtf((float)max(ds, 1));
    in_norm[i]  = rsqrtf((float)max(dd, 1));
}

// ---------------- exclusive scan (3-phase) ----------------
__global__ void scan_block_kernel(const int* __restrict__ deg, int* __restrict__ out,
                                  int* __restrict__ bsums, int N) {
    __shared__ int temp[256];
    int tid = threadIdx.x;
    int i = blockIdx.x * 256 + tid;
    int v = (i < N) ? deg[i] : 0;
    temp[tid] = v;
    __syncthreads();
    for (int off = 1; off < 256; off <<= 1) {
        int t = (tid >= off) ? temp[tid - off] : 0;
        __syncthreads();
        temp[tid] += t;
        __syncthreads();
    }
    int excl = (tid > 0) ? temp[tid - 1] : 0;
    if (i < N) out[i] = excl;
    if (tid == 255) bsums[blockIdx.x] = temp[255];
}

__global__ void scan_sums_kernel(int* __restrict__ bsums, int B) {
    __shared__ int temp[512];
    int tid = threadIdx.x;
    int v = (tid < B) ? bsums[tid] : 0;
    temp[tid] = v;
    __syncthreads();
    for (int off = 1; off < 512; off <<= 1) {
        int t = (tid >= off) ? temp[tid - off] : 0;
        __syncthreads();
        temp[tid] += t;
        __syncthreads();
    }
    int excl = (tid > 0) ? temp[tid - 1] : 0;
    if (tid < B) bsums[tid] = excl;
}

__global__ void scan_add_kernel(int* __restrict__ row_off, const int* __restrict__ bsums,
                                int N, int E) {
    int i = blockIdx.x * 256 + threadIdx.x;
    if (i < N) row_off[i] += bsums[i >> 8];
    if (i == 0) row_off[N] = E;
}

// ---------------- per-chunk base offsets (unpack u16 counts -> u32 cursors) ----------------
__global__ void chunk_base_kernel(const unsigned* __restrict__ pdst, int* __restrict__ base,
                                  const int* __restrict__ row_off, int N) {
    int i = blockIdx.x * blockDim.x + threadIdx.x;
    if (i >= N) return;
    int half = i >> 1, sh = (i & 1) << 4;
    int b = row_off[i];
#pragma unroll
    for (int c = 0; c < NCHUNK; c++) {
        int t = (pdst[(size_t)c * (N_NODES / 2) + half] >> sh) & 0xFFFF;
        base[(size_t)c * N_NODES + i] = b;
        b += t;
    }
}

// ---------------- counting-sort scatter: LDS cursors, plain global stores ----------------
__global__ __launch_bounds__(256) void scatter_sort_kernel(
        const int* __restrict__ src, const int* __restrict__ dst,
        const int* __restrict__ base, int* __restrict__ csr_src) {
    __shared__ int cur[SLICE_S];
    int slice = blockIdx.x & (NSLICE_S - 1);
    int chunk = blockIdx.x >> 3;
    int lo = slice * SLICE_S;
    const int* bp = base + (size_t)chunk * N_NODES + lo;
    for (int t = threadIdx.x; t < SLICE_S; t += 256) cur[t] = bp[t];
    __syncthreads();
    int e0 = chunk * CHUNK_E;
    for (int e = e0 + threadIdx.x; e < e0 + CHUNK_E; e += 256) {
        int d = dst[e] - lo;
        if ((unsigned)d < (unsigned)SLICE_S) {
            int p = atomicAdd(&cur[d], 1);   // LDS atomic
            csr_src[p] = src[e];
        }
    }
}

// ---------------- thread-per-row GEMM, 32-col half per blockIdx.y ----------------
template <int K>
__global__ __launch_bounds__(256, 4) void gemm_tpr_kernel(
        const float* __restrict__ in, const float* __restrict__ W,
        const float* __restrict__ scale, float* __restrict__ out, int N) {
    int r = blockIdx.x * blockDim.x + threadIdx.x;
    if (r >= N) return;
    const int h = blockIdx.y * 32;

    float acc[32];
#pragma unroll
    for (int j = 0; j < 32; j++) acc[j] = 0.f;

    const float* row = in + (size_t)r * K;
#pragma unroll 4
    for (int k = 0; k < K; k += 4) {
        float4 a = *reinterpret_cast<const float4*>(row + k);
        const float* w0 = W + (size_t)k * 64 + h;
#pragma unroll
        for (int j = 0; j < 32; j++) acc[j] = fmaf(a.x, w0[j], acc[j]);
#pragma unroll
        for (int j = 0; j < 32; j++) acc[j] = fmaf(a.y, w0[64 + j], acc[j]);
#pragma unroll
        for (int j = 0; j < 32; j++) acc[j] = fmaf(a.z, w0[128 + j], acc[j]);
#pragma unroll
        for (int j = 0; j < 32; j++) acc[j] = fmaf(a.w, w0[192 + j], acc[j]);
    }

    float s = scale[r];
    float4* o = reinterpret_cast<float4*>(out + (size_t)r * 64 + h);
#pragma unroll
    for (int j = 0; j < 32; j += 4) {
        float4 v;
        v.x = acc[j + 0] * s;
        v.y = acc[j + 1] * s;
        v.z = acc[j + 2] * s;
        v.w = acc[j + 3] * s;
        o[j >> 2] = v;
    }
}

// ---------------- CSR aggregation (one wave per node), optional fused 64->2 head ----------------
template <bool FUSE_HEAD>
__global__ __launch_bounds__(256) void agg_kernel(
        const float* __restrict__ X, const int* __restrict__ row_off,
        const int* __restrict__ csr_src, const float* __restrict__ in_norm,
        const float* __restrict__ bias, const float* __restrict__ Wm,
        const float* __restrict__ bm, float* __restrict__ out, int N) {
    int lane = threadIdx.x & 63;
    int wave = threadIdx.x >> 6;
    int v = blockIdx.x * (blockDim.x >> 6) + wave;
    if (v >= N) return;

    int start = row_off[v];
    int end = row_off[v + 1];
    float acc = 0.f;
    for (int base = start; base < end; base += 64) {
        int idx = base + lane;
        int s_e = (idx < end) ? csr_src[idx] : 0;
        int cnt = min(64, end - base);
        for (int t = 0; t < cnt; t++) {
            int s = __shfl(s_e, t);
            acc += X[(size_t)s * 64 + lane];
        }
    }
    float h = fmaf(acc, in_norm[v], bias[lane]);
    h = fmaxf(h, 0.f);

    if (!FUSE_HEAD) {
        out[(size_t)v * 64 + lane] = h;
    } else {
        float p0 = h * Wm[lane * 2 + 0];
        float p1 = h * Wm[lane * 2 + 1];
#pragma unroll
        for (int off = 32; off > 0; off >>= 1) {
            p0 += __shfl_xor(p0, off);
            p1 += __shfl_xor(p1, off);
        }
        if (lane == 0) {
            out[(size_t)v * 2 + 0] = p0 + bm[0];
            out[(size_t)v * 2 + 1] = p1 + bm[1];
        }
    }
}

extern "C" void kernel_launch(void* const* d_in, const int* in_sizes, int n_in,
                              void* d_out, int out_size, void* d_ws, size_t ws_size,
                              hipStream_t stream) {
    const float* feature = (const float*)d_in[0];
    const float* W1 = (const float*)d_in[1];
    const float* b1 = (const float*)d_in[2];
    const float* W2 = (const float*)d_in[3];
    const float* b2 = (const float*)d_in[4];
    const float* Wm = (const float*)d_in[5];
    const float* bm = (const float*)d_in[6];
    const int* src = (const int*)d_in[7];
    const int* dst = (const int*)d_in[8];
    float* out = (float*)d_out;

    const int N = N_NODES, E = N_EDGES;

    char* p = (char*)d_ws;
    int* deg_dst = (int*)p;      p += (size_t)N * 4;
    float* out_norm = (float*)p; p += (size_t)N * 4;
    float* in_norm = (float*)p;  p += (size_t)N * 4;
    int* row_off = (int*)p;      p += (size_t)(N + 1) * 4;
    int* bsums = (int*)p;        p += 512 * 4;
    int* csr_src = (int*)p;      p += (size_t)E * 4;
    float* X = (float*)p;        p += (size_t)N * 64 * 4;   // 25.6 MB
    float* H = (float*)p;        p += (size_t)N * 64 * 4;   // 25.6 MB

    // aliases (all consumed before gemm1 writes X / agg1 writes H):
    int* base = (int*)X;                                    // [NCHUNK][N]   25.6 MB
    unsigned* pdst = (unsigned*)H;                          // [NCHUNK][N/2] 12.8 MB
    unsigned* psrc = (unsigned*)H + (size_t)NCHUNK * (N_NODES / 2);  // 12.8 MB

    hist_kernel<<<NSLICE_H * NCHUNK, 256, 0, stream>>>(dst, pdst);
    hist_kernel<<<NSLICE_H * NCHUNK, 256, 0, stream>>>(src, psrc);
    reduce_norm_kernel<<<(N + 255) / 256, 256, 0, stream>>>(psrc, pdst, out_norm, in_norm,
                                                            deg_dst, N);

    int nScanBlocks = (N + 255) / 256;  // 391
    scan_block_kernel<<<nScanBlocks, 256, 0, stream>>>(deg_dst, row_off, bsums, N);
    scan_sums_kernel<<<1, 512, 0, stream>>>(bsums, nScanBlocks);
    scan_add_kernel<<<nScanBlocks, 256, 0, stream>>>(row_off, bsums, N, E);

    chunk_base_kernel<<<(N + 255) / 256, 256, 0, stream>>>(pdst, base, row_off, N);
    scatter_sort_kernel<<<NSLICE_S * NCHUNK, 256, 0, stream>>>(src, dst, base, csr_src);

    dim3 ggrid((N + 255) / 256, 2);
    // layer 1
    gemm_tpr_kernel<128><<<ggrid, 256, 0, stream>>>(feature, W1, out_norm, X, N);
    agg_kernel<false><<<(N + 3) / 4, 256, 0, stream>>>(X, row_off, csr_src, in_norm, b1,
                                                       nullptr, nullptr, H, N);
    // layer 2
    gemm_tpr_kernel<64><<<ggrid, 256, 0, stream>>>(H, W2, out_norm, X, N);
    // fused head
    agg_kernel<true><<<(N + 3) / 4, 256, 0, stream>>>(X, row_off, csr_src, in_norm, b2,
                                                      Wm, bm, out, N);
}

// Round 7
// 410.925 us; speedup vs baseline: 1.8582x; 1.1447x over previous
//
#include <hip/hip_runtime.h>

#define N_NODES 100000
#define N_EDGES 1600000
#define IN_F 128
#define H_F 64

#define NCHUNK 64
#define CHUNK_E (N_EDGES / NCHUNK)      // 25000

// histogram slicing: 2x u16 packed per u32 -> 25000 nodes in 50KB LDS
#define NSLICE_H 4
#define SLICE_H (N_NODES / NSLICE_H)    // 25000
// scatter slicing: u32 cursors -> 12500 nodes in 50KB LDS
#define NSLICE_S 8
#define SLICE_S (N_NODES / NSLICE_S)    // 12500

// ---------------- LDS histogram, packed u16 pairs ----------------
__global__ __launch_bounds__(256) void hist_kernel(
        const int* __restrict__ idx, unsigned* __restrict__ partial) {
    __shared__ unsigned hist[SLICE_H / 2];
    int slice = blockIdx.x & (NSLICE_H - 1);
    int chunk = blockIdx.x >> 2;
    int lo = slice * SLICE_H;
    for (int t = threadIdx.x; t < SLICE_H / 2; t += 256) hist[t] = 0;
    __syncthreads();
    int e0 = chunk * CHUNK_E;
    for (int e = e0 + threadIdx.x; e < e0 + CHUNK_E; e += 256) {
        int d = idx[e] - lo;
        if ((unsigned)d < (unsigned)SLICE_H)
            atomicAdd(&hist[d >> 1], 1u << ((d & 1) << 4));
    }
    __syncthreads();
    unsigned* dstp = partial + (size_t)chunk * (N_NODES / 2) + (lo >> 1);
    for (int t = threadIdx.x; t < SLICE_H / 2; t += 256) dstp[t] = hist[t];
}

// ---------------- reduce packed partials -> degrees + norms ----------------
__global__ void reduce_norm_kernel(const unsigned* __restrict__ psrc,
                                   const unsigned* __restrict__ pdst,
                                   float* __restrict__ out_norm, float* __restrict__ in_norm,
                                   int* __restrict__ deg_dst, int N) {
    int i = blockIdx.x * blockDim.x + threadIdx.x;
    if (i >= N) return;
    int half = i >> 1, sh = (i & 1) << 4;
    int ds = 0, dd = 0;
#pragma unroll
    for (int c = 0; c < NCHUNK; c++) {
        ds += (psrc[(size_t)c * (N_NODES / 2) + half] >> sh) & 0xFFFF;
        dd += (pdst[(size_t)c * (N_NODES / 2) + half] >> sh) & 0xFFFF;
    }
    deg_dst[i] = dd;
    out_norm[i] = rsqrtf((float)max(ds, 1));
    in_norm[i]  = rsqrtf((float)max(dd, 1));
}

// ---------------- exclusive scan (3-phase) ----------------
__global__ void scan_block_kernel(const int* __restrict__ deg, int* __restrict__ out,
                                  int* __restrict__ bsums, int N) {
    __shared__ int temp[256];
    int tid = threadIdx.x;
    int i = blockIdx.x * 256 + tid;
    int v = (i < N) ? deg[i] : 0;
    temp[tid] = v;
    __syncthreads();
    for (int off = 1; off < 256; off <<= 1) {
        int t = (tid >= off) ? temp[tid - off] : 0;
        __syncthreads();
        temp[tid] += t;
        __syncthreads();
    }
    int excl = (tid > 0) ? temp[tid - 1] : 0;
    if (i < N) out[i] = excl;
    if (tid == 255) bsums[blockIdx.x] = temp[255];
}

__global__ void scan_sums_kernel(int* __restrict__ bsums, int B) {
    __shared__ int temp[512];
    int tid = threadIdx.x;
    int v = (tid < B) ? bsums[tid] : 0;
    temp[tid] = v;
    __syncthreads();
    for (int off = 1; off < 512; off <<= 1) {
        int t = (tid >= off) ? temp[tid - off] : 0;
        __syncthreads();
        temp[tid] += t;
        __syncthreads();
    }
    int excl = (tid > 0) ? temp[tid - 1] : 0;
    if (tid < B) bsums[tid] = excl;
}

__global__ void scan_add_kernel(int* __restrict__ row_off, const int* __restrict__ bsums,
                                int N, int E) {
    int i = blockIdx.x * 256 + threadIdx.x;
    if (i < N) row_off[i] += bsums[i >> 8];
    if (i == 0) row_off[N] = E;
}

// ---------------- per-chunk base offsets (unpack u16 counts -> u32 cursors) ----------------
__global__ void chunk_base_kernel(const unsigned* __restrict__ pdst, int* __restrict__ base,
                                  const int* __restrict__ row_off, int N) {
    int i = blockIdx.x * blockDim.x + threadIdx.x;
    if (i >= N) return;
    int half = i >> 1, sh = (i & 1) << 4;
    int b = row_off[i];
#pragma unroll
    for (int c = 0; c < NCHUNK; c++) {
        int t = (pdst[(size_t)c * (N_NODES / 2) + half] >> sh) & 0xFFFF;
        base[(size_t)c * N_NODES + i] = b;
        b += t;
    }
}

// ---------------- counting-sort scatter: LDS cursors, plain global stores ----------------
__global__ __launch_bounds__(256) void scatter_sort_kernel(
        const int* __restrict__ src, const int* __restrict__ dst,
        const int* __restrict__ base, int* __restrict__ csr_src) {
    __shared__ int cur[SLICE_S];
    int slice = blockIdx.x & (NSLICE_S - 1);
    int chunk = blockIdx.x >> 3;
    int lo = slice * SLICE_S;
    const int* bp = base + (size_t)chunk * N_NODES + lo;
    for (int t = threadIdx.x; t < SLICE_S; t += 256) cur[t] = bp[t];
    __syncthreads();
    int e0 = chunk * CHUNK_E;
    for (int e = e0 + threadIdx.x; e < e0 + CHUNK_E; e += 256) {
        int d = dst[e] - lo;
        if ((unsigned)d < (unsigned)SLICE_S) {
            int p = atomicAdd(&cur[d], 1);   // LDS atomic
            csr_src[p] = src[e];
        }
    }
}

// ---------------- thread-per-row GEMM, 32-col half per blockIdx.y ----------------
template <int K>
__global__ __launch_bounds__(256, 4) void gemm_tpr_kernel(
        const float* __restrict__ in, const float* __restrict__ W,
        const float* __restrict__ scale, float* __restrict__ out, int N) {
    int r = blockIdx.x * blockDim.x + threadIdx.x;
    if (r >= N) return;
    const int h = blockIdx.y * 32;

    float acc[32];
#pragma unroll
    for (int j = 0; j < 32; j++) acc[j] = 0.f;

    const float* row = in + (size_t)r * K;
#pragma unroll 4
    for (int k = 0; k < K; k += 4) {
        float4 a = *reinterpret_cast<const float4*>(row + k);
        const float* w0 = W + (size_t)k * 64 + h;
#pragma unroll
        for (int j = 0; j < 32; j++) acc[j] = fmaf(a.x, w0[j], acc[j]);
#pragma unroll
        for (int j = 0; j < 32; j++) acc[j] = fmaf(a.y, w0[64 + j], acc[j]);
#pragma unroll
        for (int j = 0; j < 32; j++) acc[j] = fmaf(a.z, w0[128 + j], acc[j]);
#pragma unroll
        for (int j = 0; j < 32; j++) acc[j] = fmaf(a.w, w0[192 + j], acc[j]);
    }

    float s = scale[r];
    float4* o = reinterpret_cast<float4*>(out + (size_t)r * 64 + h);
#pragma unroll
    for (int j = 0; j < 32; j += 4) {
        float4 v;
        v.x = acc[j + 0] * s;
        v.y = acc[j + 1] * s;
        v.z = acc[j + 2] * s;
        v.w = acc[j + 3] * s;
        o[j >> 2] = v;
    }
}

// ---------------- CSR aggregation: scalar index loads + 8-deep gather batching ----------------
// start/end forced to SGPR (readfirstlane) -> csr_src[start+t] is a wave-uniform
// address -> s_load through K$ (contiguous, batches to dwordx). 8 independent
// gathers in flight per wave; pairwise-tree accumulate (deterministic order).
template <bool FUSE_HEAD>
__global__ __launch_bounds__(256) void agg_kernel(
        const float* __restrict__ X, const int* __restrict__ row_off,
        const int* __restrict__ csr_src, const float* __restrict__ in_norm,
        const float* __restrict__ bias, const float* __restrict__ Wm,
        const float* __restrict__ bm, float* __restrict__ out, int N) {
    int lane = threadIdx.x & 63;
    int wave = threadIdx.x >> 6;
    int v = blockIdx.x * (blockDim.x >> 6) + wave;
    if (v >= N) return;

    int start = __builtin_amdgcn_readfirstlane(row_off[v]);
    int end   = __builtin_amdgcn_readfirstlane(row_off[v + 1]);
    int deg = end - start;
    const int* __restrict__ idxp = csr_src + start;

    float acc = 0.f;
    int t = 0;
    for (; t + 8 <= deg; t += 8) {
        int s0 = idxp[t + 0], s1 = idxp[t + 1], s2 = idxp[t + 2], s3 = idxp[t + 3];
        int s4 = idxp[t + 4], s5 = idxp[t + 5], s6 = idxp[t + 6], s7 = idxp[t + 7];
        float a0 = X[(size_t)s0 * 64 + lane];
        float a1 = X[(size_t)s1 * 64 + lane];
        float a2 = X[(size_t)s2 * 64 + lane];
        float a3 = X[(size_t)s3 * 64 + lane];
        float a4 = X[(size_t)s4 * 64 + lane];
        float a5 = X[(size_t)s5 * 64 + lane];
        float a6 = X[(size_t)s6 * 64 + lane];
        float a7 = X[(size_t)s7 * 64 + lane];
        acc += (((a0 + a1) + (a2 + a3)) + ((a4 + a5) + (a6 + a7)));
    }
    for (; t < deg; t++) {
        int s = idxp[t];
        acc += X[(size_t)s * 64 + lane];
    }

    float h = fmaf(acc, in_norm[v], bias[lane]);
    h = fmaxf(h, 0.f);

    if (!FUSE_HEAD) {
        out[(size_t)v * 64 + lane] = h;
    } else {
        float p0 = h * Wm[lane * 2 + 0];
        float p1 = h * Wm[lane * 2 + 1];
#pragma unroll
        for (int off = 32; off > 0; off >>= 1) {
            p0 += __shfl_xor(p0, off);
            p1 += __shfl_xor(p1, off);
        }
        if (lane == 0) {
            out[(size_t)v * 2 + 0] = p0 + bm[0];
            out[(size_t)v * 2 + 1] = p1 + bm[1];
        }
    }
}

extern "C" void kernel_launch(void* const* d_in, const int* in_sizes, int n_in,
                              void* d_out, int out_size, void* d_ws, size_t ws_size,
                              hipStream_t stream) {
    const float* feature = (const float*)d_in[0];
    const float* W1 = (const float*)d_in[1];
    const float* b1 = (const float*)d_in[2];
    const float* W2 = (const float*)d_in[3];
    const float* b2 = (const float*)d_in[4];
    const float* Wm = (const float*)d_in[5];
    const float* bm = (const float*)d_in[6];
    const int* src = (const int*)d_in[7];
    const int* dst = (const int*)d_in[8];
    float* out = (float*)d_out;

    const int N = N_NODES, E = N_EDGES;

    char* p = (char*)d_ws;
    int* deg_dst = (int*)p;      p += (size_t)N * 4;
    float* out_norm = (float*)p; p += (size_t)N * 4;
    float* in_norm = (float*)p;  p += (size_t)N * 4;
    int* row_off = (int*)p;      p += (size_t)(N + 1) * 4;
    int* bsums = (int*)p;        p += 512 * 4;
    int* csr_src = (int*)p;      p += (size_t)E * 4;
    float* X = (float*)p;        p += (size_t)N * 64 * 4;   // 25.6 MB
    float* H = (float*)p;        p += (size_t)N * 64 * 4;   // 25.6 MB

    // aliases (all consumed before gemm1 writes X / agg1 writes H):
    int* base = (int*)X;                                    // [NCHUNK][N]   25.6 MB
    unsigned* pdst = (unsigned*)H;                          // [NCHUNK][N/2] 12.8 MB
    unsigned* psrc = (unsigned*)H + (size_t)NCHUNK * (N_NODES / 2);  // 12.8 MB

    hist_kernel<<<NSLICE_H * NCHUNK, 256, 0, stream>>>(dst, pdst);
    hist_kernel<<<NSLICE_H * NCHUNK, 256, 0, stream>>>(src, psrc);
    reduce_norm_kernel<<<(N + 255) / 256, 256, 0, stream>>>(psrc, pdst, out_norm, in_norm,
                                                            deg_dst, N);

    int nScanBlocks = (N + 255) / 256;  // 391
    scan_block_kernel<<<nScanBlocks, 256, 0, stream>>>(deg_dst, row_off, bsums, N);
    scan_sums_kernel<<<1, 512, 0, stream>>>(bsums, nScanBlocks);
    scan_add_kernel<<<nScanBlocks, 256, 0, stream>>>(row_off, bsums, N, E);

    chunk_base_kernel<<<(N + 255) / 256, 256, 0, stream>>>(pdst, base, row_off, N);
    scatter_sort_kernel<<<NSLICE_S * NCHUNK, 256, 0, stream>>>(src, dst, base, csr_src);

    dim3 ggrid((N + 255) / 256, 2);
    // layer 1
    gemm_tpr_kernel<128><<<ggrid, 256, 0, stream>>>(feature, W1, out_norm, X, N);
    agg_kernel<false><<<(N + 3) / 4, 256, 0, stream>>>(X, row_off, csr_src, in_norm, b1,
                                                       nullptr, nullptr, H, N);
    // layer 2
    gemm_tpr_kernel<64><<<ggrid, 256, 0, stream>>>(H, W2, out_norm, X, N);
    // fused head
    agg_kernel<true><<<(N + 3) / 4, 256, 0, stream>>>(X, row_off, csr_src, in_norm, b2,
                                                      Wm, bm, out, N);
}

// Round 8
// 376.756 us; speedup vs baseline: 2.0268x; 1.0907x over previous
//
#include <hip/hip_runtime.h>

#define N_NODES 100000
#define N_EDGES 1600000
#define IN_F 128
#define H_F 64

#define NCHUNK 64
#define CHUNK_E (N_EDGES / NCHUNK)      // 25000

// histogram slicing: 2x u16 packed per u32 -> 25000 nodes in 50KB LDS
#define NSLICE_H 4
#define SLICE_H (N_NODES / NSLICE_H)    // 25000
// scatter slicing: u32 cursors -> 12500 nodes in 50KB LDS
#define NSLICE_S 8
#define SLICE_S (N_NODES / NSLICE_S)    // 12500

// ---------------- LDS histogram, packed u16 pairs; y=0 -> dst, y=1 -> src ----------------
__global__ __launch_bounds__(256) void hist_both_kernel(
        const int* __restrict__ dst, const int* __restrict__ src,
        unsigned* __restrict__ pdst, unsigned* __restrict__ psrc) {
    __shared__ unsigned hist[SLICE_H / 2];
    const int* idx = blockIdx.y ? src : dst;
    unsigned* partial = blockIdx.y ? psrc : pdst;
    int slice = blockIdx.x & (NSLICE_H - 1);
    int chunk = blockIdx.x >> 2;
    int lo = slice * SLICE_H;
    for (int t = threadIdx.x; t < SLICE_H / 2; t += 256) hist[t] = 0;
    __syncthreads();
    int e0 = chunk * CHUNK_E;
    for (int e = e0 + threadIdx.x; e < e0 + CHUNK_E; e += 256) {
        int d = idx[e] - lo;
        if ((unsigned)d < (unsigned)SLICE_H)
            atomicAdd(&hist[d >> 1], 1u << ((d & 1) << 4));
    }
    __syncthreads();
    unsigned* dstp = partial + (size_t)chunk * (N_NODES / 2) + (lo >> 1);
    for (int t = threadIdx.x; t < SLICE_H / 2; t += 256) dstp[t] = hist[t];
}

// ---------------- reduce partials -> norms + block-level scan of deg_dst ----------------
__global__ void reduce_norm_scan_kernel(const unsigned* __restrict__ psrc,
                                        const unsigned* __restrict__ pdst,
                                        float* __restrict__ out_norm, float* __restrict__ in_norm,
                                        int* __restrict__ row_off, int* __restrict__ bsums, int N) {
    __shared__ int temp[256];
    int tid = threadIdx.x;
    int i = blockIdx.x * 256 + tid;
    int ds = 0, dd = 0;
    if (i < N) {
        int half = i >> 1, sh = (i & 1) << 4;
#pragma unroll
        for (int c = 0; c < NCHUNK; c++) {
            ds += (psrc[(size_t)c * (N_NODES / 2) + half] >> sh) & 0xFFFF;
            dd += (pdst[(size_t)c * (N_NODES / 2) + half] >> sh) & 0xFFFF;
        }
        out_norm[i] = rsqrtf((float)max(ds, 1));
        in_norm[i]  = rsqrtf((float)max(dd, 1));
    }
    temp[tid] = dd;
    __syncthreads();
    for (int off = 1; off < 256; off <<= 1) {
        int t = (tid >= off) ? temp[tid - off] : 0;
        __syncthreads();
        temp[tid] += t;
        __syncthreads();
    }
    int excl = (tid > 0) ? temp[tid - 1] : 0;
    if (i < N) row_off[i] = excl;
    if (tid == 255) bsums[blockIdx.x] = temp[255];
}

__global__ void scan_sums_kernel(int* __restrict__ bsums, int B) {
    __shared__ int temp[512];
    int tid = threadIdx.x;
    int v = (tid < B) ? bsums[tid] : 0;
    temp[tid] = v;
    __syncthreads();
    for (int off = 1; off < 512; off <<= 1) {
        int t = (tid >= off) ? temp[tid - off] : 0;
        __syncthreads();
        temp[tid] += t;
        __syncthreads();
    }
    int excl = (tid > 0) ? temp[tid - 1] : 0;
    if (tid < B) bsums[tid] = excl;
}

// ---------------- finalize row_off + emit per-chunk base cursors ----------------
__global__ void scan_add_base_kernel(int* __restrict__ row_off, const int* __restrict__ bsums,
                                     const unsigned* __restrict__ pdst, int* __restrict__ base,
                                     int N, int E) {
    int i = blockIdx.x * 256 + threadIdx.x;
    if (i < N) {
        int r = row_off[i] + bsums[i >> 8];
        row_off[i] = r;
        int half = i >> 1, sh = (i & 1) << 4;
        int b = r;
#pragma unroll
        for (int c = 0; c < NCHUNK; c++) {
            int t = (pdst[(size_t)c * (N_NODES / 2) + half] >> sh) & 0xFFFF;
            base[(size_t)c * N_NODES + i] = b;
            b += t;
        }
    }
    if (i == 0) row_off[N] = E;
}

// ---------------- counting-sort scatter: LDS cursors, plain global stores ----------------
__global__ __launch_bounds__(256) void scatter_sort_kernel(
        const int* __restrict__ src, const int* __restrict__ dst,
        const int* __restrict__ base, int* __restrict__ csr_src) {
    __shared__ int cur[SLICE_S];
    int slice = blockIdx.x & (NSLICE_S - 1);
    int chunk = blockIdx.x >> 3;
    int lo = slice * SLICE_S;
    const int* bp = base + (size_t)chunk * N_NODES + lo;
    for (int t = threadIdx.x; t < SLICE_S; t += 256) cur[t] = bp[t];
    __syncthreads();
    int e0 = chunk * CHUNK_E;
    for (int e = e0 + threadIdx.x; e < e0 + CHUNK_E; e += 256) {
        int d = dst[e] - lo;
        if ((unsigned)d < (unsigned)SLICE_S) {
            int p = atomicAdd(&cur[d], 1);   // LDS atomic
            csr_src[p] = src[e];
        }
    }
}

// ---------------- thread-per-row GEMM, 32-col half per blockIdx.y ----------------
template <int K>
__global__ __launch_bounds__(256, 4) void gemm_tpr_kernel(
        const float* __restrict__ in, const float* __restrict__ W,
        const float* __restrict__ scale, float* __restrict__ out, int N) {
    int r = blockIdx.x * blockDim.x + threadIdx.x;
    if (r >= N) return;
    const int h = blockIdx.y * 32;

    float acc[32];
#pragma unroll
    for (int j = 0; j < 32; j++) acc[j] = 0.f;

    const float* row = in + (size_t)r * K;
#pragma unroll 4
    for (int k = 0; k < K; k += 4) {
        float4 a = *reinterpret_cast<const float4*>(row + k);
        const float* w0 = W + (size_t)k * 64 + h;
#pragma unroll
        for (int j = 0; j < 32; j++) acc[j] = fmaf(a.x, w0[j], acc[j]);
#pragma unroll
        for (int j = 0; j < 32; j++) acc[j] = fmaf(a.y, w0[64 + j], acc[j]);
#pragma unroll
        for (int j = 0; j < 32; j++) acc[j] = fmaf(a.z, w0[128 + j], acc[j]);
#pragma unroll
        for (int j = 0; j < 32; j++) acc[j] = fmaf(a.w, w0[192 + j], acc[j]);
    }

    float s = scale[r];
    float4* o = reinterpret_cast<float4*>(out + (size_t)r * 64 + h);
#pragma unroll
    for (int j = 0; j < 32; j += 4) {
        float4 v;
        v.x = acc[j + 0] * s;
        v.y = acc[j + 1] * s;
        v.z = acc[j + 2] * s;
        v.w = acc[j + 3] * s;
        o[j >> 2] = v;
    }
}

// ---------------- CSR aggregation: scalar index loads + 16-deep gather batching ----------------
template <bool FUSE_HEAD>
__global__ __launch_bounds__(256) void agg_kernel(
        const float* __restrict__ X, const int* __restrict__ row_off,
        const int* __restrict__ csr_src, const float* __restrict__ in_norm,
        const float* __restrict__ bias, const float* __restrict__ Wm,
        const float* __restrict__ bm, float* __restrict__ out, int N) {
    int lane = threadIdx.x & 63;
    int wave = threadIdx.x >> 6;
    int v = blockIdx.x * (blockDim.x >> 6) + wave;
    if (v >= N) return;

    int start = __builtin_amdgcn_readfirstlane(row_off[v]);
    int end   = __builtin_amdgcn_readfirstlane(row_off[v + 1]);
    int deg = end - start;
    const int* __restrict__ idxp = csr_src + start;

    float acc0 = 0.f, acc1 = 0.f;
    int t = 0;
    for (; t + 16 <= deg; t += 16) {
        int s[16];
#pragma unroll
        for (int u = 0; u < 16; u++) s[u] = idxp[t + u];
        float a[16];
#pragma unroll
        for (int u = 0; u < 16; u++) a[u] = X[(size_t)s[u] * 64 + lane];
        acc0 += (((a[0] + a[1]) + (a[2] + a[3])) + ((a[4] + a[5]) + (a[6] + a[7])));
        acc1 += (((a[8] + a[9]) + (a[10] + a[11])) + ((a[12] + a[13]) + (a[14] + a[15])));
    }
    for (; t + 8 <= deg; t += 8) {
        int s[8];
#pragma unroll
        for (int u = 0; u < 8; u++) s[u] = idxp[t + u];
        float a[8];
#pragma unroll
        for (int u = 0; u < 8; u++) a[u] = X[(size_t)s[u] * 64 + lane];
        acc0 += (((a[0] + a[1]) + (a[2] + a[3])) + ((a[4] + a[5]) + (a[6] + a[7])));
    }
    for (; t < deg; t++) {
        int s = idxp[t];
        acc0 += X[(size_t)s * 64 + lane];
    }
    float acc = acc0 + acc1;

    float h = fmaf(acc, in_norm[v], bias[lane]);
    h = fmaxf(h, 0.f);

    if (!FUSE_HEAD) {
        out[(size_t)v * 64 + lane] = h;
    } else {
        float p0 = h * Wm[lane * 2 + 0];
        float p1 = h * Wm[lane * 2 + 1];
#pragma unroll
        for (int off = 32; off > 0; off >>= 1) {
            p0 += __shfl_xor(p0, off);
            p1 += __shfl_xor(p1, off);
        }
        if (lane == 0) {
            out[(size_t)v * 2 + 0] = p0 + bm[0];
            out[(size_t)v * 2 + 1] = p1 + bm[1];
        }
    }
}

extern "C" void kernel_launch(void* const* d_in, const int* in_sizes, int n_in,
                              void* d_out, int out_size, void* d_ws, size_t ws_size,
                              hipStream_t stream) {
    const float* feature = (const float*)d_in[0];
    const float* W1 = (const float*)d_in[1];
    const float* b1 = (const float*)d_in[2];
    const float* W2 = (const float*)d_in[3];
    const float* b2 = (const float*)d_in[4];
    const float* Wm = (const float*)d_in[5];
    const float* bm = (const float*)d_in[6];
    const int* src = (const int*)d_in[7];
    const int* dst = (const int*)d_in[8];
    float* out = (float*)d_out;

    const int N = N_NODES, E = N_EDGES;

    char* p = (char*)d_ws;
    float* out_norm = (float*)p; p += (size_t)N * 4;
    float* in_norm = (float*)p;  p += (size_t)N * 4;
    int* row_off = (int*)p;      p += (size_t)(N + 1) * 4;
    int* bsums = (int*)p;        p += 512 * 4;
    int* csr_src = (int*)p;      p += (size_t)E * 4;
    float* X = (float*)p;        p += (size_t)N * 64 * 4;   // 25.6 MB
    float* H = (float*)p;        p += (size_t)N * 64 * 4;   // 25.6 MB

    // aliases (all consumed before gemm1 writes X / agg1 writes H):
    int* base = (int*)X;                                    // [NCHUNK][N]   25.6 MB
    unsigned* pdst = (unsigned*)H;                          // [NCHUNK][N/2] 12.8 MB
    unsigned* psrc = (unsigned*)H + (size_t)NCHUNK * (N_NODES / 2);  // 12.8 MB

    dim3 hgrid(NSLICE_H * NCHUNK, 2);
    hist_both_kernel<<<hgrid, 256, 0, stream>>>(dst, src, pdst, psrc);

    int nScanBlocks = (N + 255) / 256;  // 391
    reduce_norm_scan_kernel<<<nScanBlocks, 256, 0, stream>>>(psrc, pdst, out_norm, in_norm,
                                                             row_off, bsums, N);
    scan_sums_kernel<<<1, 512, 0, stream>>>(bsums, nScanBlocks);
    scan_add_base_kernel<<<nScanBlocks, 256, 0, stream>>>(row_off, bsums, pdst, base, N, E);

    scatter_sort_kernel<<<NSLICE_S * NCHUNK, 256, 0, stream>>>(src, dst, base, csr_src);

    dim3 ggrid((N + 255) / 256, 2);
    // layer 1
    gemm_tpr_kernel<128><<<ggrid, 256, 0, stream>>>(feature, W1, out_norm, X, N);
    agg_kernel<false><<<(N + 3) / 4, 256, 0, stream>>>(X, row_off, csr_src, in_norm, b1,
                                                       nullptr, nullptr, H, N);
    // layer 2
    gemm_tpr_kernel<64><<<ggrid, 256, 0, stream>>>(H, W2, out_norm, X, N);
    // fused head
    agg_kernel<true><<<(N + 3) / 4, 256, 0, stream>>>(X, row_off, csr_src, in_norm, b2,
                                                      Wm, bm, out, N);
}